// Round 10
// baseline (154.014 us; speedup 1.0000x reference)
//
#include <hip/hip_runtime.h>

typedef __bf16 bf16x8 __attribute__((ext_vector_type(8)));
typedef float floatx4 __attribute__((ext_vector_type(4)));

// split fp32 -> bf16 hi + bf16 lo (x ~= hi + lo, residual ~2^-17)
__device__ inline void cvt8_hl(const float* __restrict__ p, bf16x8& h, bf16x8& l){
  float4 v0 = *reinterpret_cast<const float4*>(p);
  float4 v1 = *reinterpret_cast<const float4*>(p + 4);
  float v[8] = {v0.x, v0.y, v0.z, v0.w, v1.x, v1.y, v1.z, v1.w};
  #pragma unroll
  for (int i = 0; i < 8; ++i) {
    __bf16 hi = (__bf16)v[i];
    h[i] = hi;
    l[i] = (__bf16)(v[i] - (float)hi);
  }
}

__device__ inline void cvt8v(float4 v0, float4 v1, bf16x8& h, bf16x8& l){
  float v[8] = {v0.x, v0.y, v0.z, v0.w, v1.x, v1.y, v1.z, v1.w};
  #pragma unroll
  for (int i = 0; i < 8; ++i) {
    __bf16 hi = (__bf16)v[i];
    h[i] = hi;
    l[i] = (__bf16)(v[i] - (float)hi);
  }
}

// async global->LDS, 16B/lane; LDS dest wave-uniform base + lane*16.
__device__ inline void gload_lds16(const float* g, float* l){
  __builtin_amdgcn_global_load_lds(
      (const __attribute__((address_space(1))) unsigned int*)g,
      (__attribute__((address_space(3))) unsigned int*)l, 16, 0, 0);
}

// ---------------------------------------------------------------------------
// K1 v10: mod[b,ff] = xt * silu(xg). M=64, N=8192, K=1024.
// R9 accounting fix: k1 (31us) is the last big controllable item; limiter is
// per-CU in-flight bytes (~4KB VGPR-hoisted vs 9.2KB BW-latency product).
// Redesign: 512 blocks x 256 thr; waves split B (one 16x16 m-tile each, full
// K) -> no cross-wave reduce, acc = 8 VGPR. W staged via global_load_lds
// width-16, double-buffered 16KB chunks (32KB LDS, 2 blocks/CU = 32KB
// in-flight/CU >> 9.2KB). XOR swizzle both-sides (R1-proven lines): LDS
// linear, global source col ^= ((row&7)<<4), ds_read addr ^= ((r16&7)<<4).
// ---------------------------------------------------------------------------
__global__ __launch_bounds__(256) void k1_gemm(
    const float* __restrict__ x,
    const float* __restrict__ Wt,
    const float* __restrict__ Wg,
    float* __restrict__ mod)
{
  __shared__ __align__(16) float wlds[2][2][16 * 128];  // [buf][mat] 32 KB
  const int tid  = threadIdx.x;
  const int wave = tid >> 6, lane = tid & 63;
  const int quad = lane >> 4, r16 = lane & 15;
  const int ffbase = blockIdx.x * 16;

  // staging: 16 gload_lds per chunk (2 mats x 8 row-pairs); wave takes 4.
  // instr t: mat = t>>3, rowpair = (t&7)*2; lanes 0-31 -> rowpair, 32-63 -> +1
  int soff[4], sdst[4];
  #pragma unroll
  for (int u = 0; u < 4; ++u) {
    int t = wave * 4 + u;
    int mat = t >> 3, rowpair = (t & 7) * 2;
    int row = rowpair + (lane >> 5);
    int cb  = (lane & 31) * 16;
    soff[u] = (ffbase + row) * 1024 + ((cb ^ ((row & 7) << 4)) >> 2);
    sdst[u] = mat * 2048 + rowpair * 128;    // float index within wlds[buf]
    soff[u] = mat ? soff[u] : soff[u];       // keep mat via sdst; src below
  }
  // source matrix per instr (mat bit of t): resolved branchlessly at use
  const int m0 = (wave * 4 + 0) >> 3, m1 = (wave * 4 + 1) >> 3;
  const int m2 = (wave * 4 + 2) >> 3, m3 = (wave * 4 + 3) >> 3;

  auto STAGE = [&](int buf, int kc) {
    gload_lds16((m0 ? Wg : Wt) + soff[0] + kc, &wlds[buf][0][0] + sdst[0]);
    gload_lds16((m1 ? Wg : Wt) + soff[1] + kc, &wlds[buf][0][0] + sdst[1]);
    gload_lds16((m2 ? Wg : Wt) + soff[2] + kc, &wlds[buf][0][0] + sdst[2]);
    gload_lds16((m3 ? Wg : Wt) + soff[3] + kc, &wlds[buf][0][0] + sdst[3]);
  };

  const float* xp = x + (wave * 16 + r16) * 1024;   // + kc + kk*32 + quad*8
  const int rowb = r16 * 512;                       // LDS row byte offset
  const int xr   = (r16 & 7) << 4;                  // read-side XOR

  floatx4 accT = (floatx4)0.0f, accG = (floatx4)0.0f;

  STAGE(0, 0);
  __syncthreads();

  #pragma unroll
  for (int c = 0; c < 8; ++c) {
    const int kc = c * 128;
    if (c < 7) STAGE((c + 1) & 1, kc + 128);
    const char* tT = (const char*)&wlds[c & 1][0][0];
    const char* tG = (const char*)&wlds[c & 1][1][0];
    #pragma unroll
    for (int kk = 0; kk < 4; ++kk) {
      const int cb  = kk * 128 + quad * 32;
      const int aLo = rowb + (cb ^ xr);
      const int aHi = rowb + ((cb + 16) ^ xr);
      bf16x8 ah, al, bth, btl, bgh, bgl;
      cvt8_hl(xp + kc + kk * 32 + quad * 8, ah, al);
      cvt8v(*reinterpret_cast<const float4*>(tT + aLo),
            *reinterpret_cast<const float4*>(tT + aHi), bth, btl);
      cvt8v(*reinterpret_cast<const float4*>(tG + aLo),
            *reinterpret_cast<const float4*>(tG + aHi), bgh, bgl);
      accT = __builtin_amdgcn_mfma_f32_16x16x32_bf16(ah, bth, accT, 0, 0, 0);
      accT = __builtin_amdgcn_mfma_f32_16x16x32_bf16(ah, btl, accT, 0, 0, 0);
      accT = __builtin_amdgcn_mfma_f32_16x16x32_bf16(al, bth, accT, 0, 0, 0);
      accG = __builtin_amdgcn_mfma_f32_16x16x32_bf16(ah, bgh, accG, 0, 0, 0);
      accG = __builtin_amdgcn_mfma_f32_16x16x32_bf16(ah, bgl, accG, 0, 0, 0);
      accG = __builtin_amdgcn_mfma_f32_16x16x32_bf16(al, bgh, accG, 0, 0, 0);
    }
    __syncthreads();
  }

  // epilogue: wave owns b-tile wave*16..+15 completely — direct store
  #pragma unroll
  for (int r = 0; r < 4; ++r) {
    float t = accT[r];
    float g = accG[r];
    float sig = 1.0f / (1.0f + __expf(-g));
    const int b = wave * 16 + quad * 4 + r;     // C/D: row = quad*4 + reg
    mod[b * 8192 + ffbase + r16] = t * g * sig;
  }
}

// ---------------------------------------------------------------------------
// K1b (R9 proven): s[b*4+k] = rsqrt(mean(|mod[b,k,:]|) + eps) + weight warm.
// ---------------------------------------------------------------------------
__global__ __launch_bounds__(256) void k1b_scale(const float* __restrict__ mod,
                                                 const float* __restrict__ wmod,
                                                 const float* __restrict__ wstat,
                                                 float* __restrict__ s)
{
  const int row = blockIdx.x;
  const int tid = threadIdx.x;
  const float* p = mod + row * 2048;

  const int g = blockIdx.x * 256 + tid;
  const float4 wv = reinterpret_cast<const float4*>(wmod)[g];
  const float4 sv = reinterpret_cast<const float4*>(wstat)[g];
  float keep = wv.x + wv.y + wv.z + wv.w + sv.x + sv.y + sv.z + sv.w;
  asm volatile("" :: "v"(keep));

  float sum = 0.0f;
  #pragma unroll
  for (int q = 0; q < 8; ++q) sum += fabsf(p[q * 256 + tid]);
  #pragma unroll
  for (int o = 1; o < 64; o <<= 1) sum += __shfl_xor(sum, o, 64);
  __shared__ float ls[4];
  if ((tid & 63) == 0) ls[tid >> 6] = sum;
  __syncthreads();
  if (tid == 0) {
    float t = ls[0] + ls[1] + ls[2] + ls[3];
    s[row] = rsqrtf(t * (1.0f / 2048.0f) + 1e-4f);
  }
}

// ---------------------------------------------------------------------------
// K2 (R9 proven, byte-identical).
// ---------------------------------------------------------------------------
__global__ __launch_bounds__(256) void k2_mag(
    const float* __restrict__ mod, const float* __restrict__ s,
    const float* __restrict__ wstat,
    const float* __restrict__ wmod,
    const float* __restrict__ cw,
    const float* __restrict__ cb,
    float* __restrict__ partial)
{
  const int b = blockIdx.x, jc = blockIdx.y;
  const int tid = threadIdx.x;
  __shared__ __align__(16) float a_l[256 * 8];

  float weff[4]; float beff = 0.0f;
  #pragma unroll
  for (int r = 0; r < 4; ++r) {
    weff[r] = cw[r] + cw[4 + r] + cw[8 + r] + cw[12 + r];
    beff += cb[r];
  }
  const float s0 = s[b * 4 + 0], s1 = s[b * 4 + 1];
  const float* mb = mod + b * 8192;

  #pragma unroll
  for (int p = 0; p < 8; ++p) {
    int k = p >> 2, r = p & 3;
    float sc = (k ? s1 : s0) * weff[r];
    a_l[tid * 8 + p] = mb[k * 2048 + r * 512 + tid] * sc;
  }
  const int j = jc * 32 + (tid & 31);
  float bp[8];
  #pragma unroll
  for (int p = 0; p < 8; ++p) {
    int k = p >> 2, r = p & 3;
    bp[p] = mb[k * 2048 + r * 512 + 256 + j] * (k ? s1 : s0);
  }
  __syncthreads();

  const int ioff = tid >> 5;
  float acc = 0.0f;
  #pragma unroll 8
  for (int it = 0; it < 32; ++it) {
    const int i = it * 8 + ioff;
    const float4 av0 = *reinterpret_cast<const float4*>(&a_l[i * 8]);
    const float4 av1 = *reinterpret_cast<const float4*>(&a_l[i * 8 + 4]);
    float d0 = av0.x * bp[0] + av0.y * bp[1] + av0.z * bp[2] + av0.w * bp[3];
    float d1 = av1.x * bp[4] + av1.y * bp[5] + av1.z * bp[6] + av1.w * bp[7];
    const int ij = i * 256 + j;
    float m0 = wmod[ij] * (d0 + beff);
    float m1 = wmod[65536 + ij] * (d1 + beff);
    float2 a1 = *reinterpret_cast<const float2*>(wstat + 131072 + ij * 2);
    float re = a1.x * m0 - a1.y * m1;
    float im = a1.x * m1 - a1.y * m0;
    acc += sqrtf(re * re + im * im + 1e-4f);
  }
  #pragma unroll
  for (int o = 1; o < 64; o <<= 1) acc += __shfl_xor(acc, o, 64);
  __shared__ float wsum[4];
  if ((tid & 63) == 0) wsum[tid >> 6] = acc;
  __syncthreads();
  if (tid == 0) partial[b * 8 + jc] = wsum[0] + wsum[1] + wsum[2] + wsum[3];
}

// ---------------------------------------------------------------------------
// K4 (R9 proven, byte-identical).
// ---------------------------------------------------------------------------
__global__ __launch_bounds__(256) void k4_out(
    const float* __restrict__ mod, const float* __restrict__ s,
    const float* __restrict__ wstat,
    const float* __restrict__ wmod,
    const float* __restrict__ cw,
    const float* __restrict__ cb,
    const float* __restrict__ partial,
    float* __restrict__ out)
{
  const int b = blockIdx.x, ibase = blockIdx.y * 32;
  const int tid = threadIdx.x;
  __shared__ __align__(16) float a_l[32 * 16];

  float weff[4]; float beff = 0.0f;
  #pragma unroll
  for (int r = 0; r < 4; ++r) {
    weff[r] = cw[r] + cw[4 + r] + cw[8 + r] + cw[12 + r];
    beff += cb[r];
  }
  float sk[4];
  #pragma unroll
  for (int k = 0; k < 4; ++k) sk[k] = s[b * 4 + k];
  const float* mb = mod + b * 8192;

  float tot = 0.0f;
  #pragma unroll
  for (int t = 0; t < 8; ++t) tot += partial[b * 8 + t];
  const float inv = rsqrtf(tot * (1.0f / 65536.0f) + 1e-4f);

  #pragma unroll
  for (int p = 0; p < 2; ++p) {
    int idx = p * 256 + tid;
    int il = idx & 31, kr = idx >> 5;
    int k = kr >> 2, r = kr & 3;
    a_l[il * 16 + kr] = mb[k * 2048 + r * 512 + ibase + il] * (sk[k] * weff[r]);
  }
  const int j = (tid & 127) * 2;
  const int ioff = tid >> 7;
  float bp0[16], bp1[16];
  #pragma unroll
  for (int kr = 0; kr < 16; ++kr) {
    int k = kr >> 2, r = kr & 3;
    float2 v = *reinterpret_cast<const float2*>(mb + k * 2048 + r * 512 + 256 + j);
    bp0[kr] = v.x * sk[k]; bp1[kr] = v.y * sk[k];
  }
  __syncthreads();

  #pragma unroll 4
  for (int it = 0; it < 16; ++it) {
    const int il = it * 2 + ioff;
    const int i = ibase + il;
    const float4 a0 = *reinterpret_cast<const float4*>(&a_l[il * 16]);
    const float4 a1 = *reinterpret_cast<const float4*>(&a_l[il * 16 + 4]);
    const float4 a2 = *reinterpret_cast<const float4*>(&a_l[il * 16 + 8]);
    const float4 a3 = *reinterpret_cast<const float4*>(&a_l[il * 16 + 12]);
    const int ij = i * 256 + j;
    const float2 wm0 = *reinterpret_cast<const float2*>(wmod + ij);
    const float2 wm1 = *reinterpret_cast<const float2*>(wmod + 65536 + ij);
    const float2 wm2 = *reinterpret_cast<const float2*>(wmod + 131072 + ij);
    const float2 wm3 = *reinterpret_cast<const float2*>(wmod + 196608 + ij);
    const float4 A0v = *reinterpret_cast<const float4*>(wstat + ij * 2);
    const float4 A1v = *reinterpret_cast<const float4*>(wstat + 131072 + ij * 2);
    float outv[2];
    #pragma unroll
    for (int e = 0; e < 2; ++e) {
      const float* bp = e ? bp1 : bp0;
      float d0 = a0.x * bp[0] + a0.y * bp[1] + a0.z * bp[2] + a0.w * bp[3];
      float d1 = a1.x * bp[4] + a1.y * bp[5] + a1.z * bp[6] + a1.w * bp[7];
      float d2 = a2.x * bp[8] + a2.y * bp[9] + a2.z * bp[10] + a2.w * bp[11];
      float d3 = a3.x * bp[12] + a3.y * bp[13] + a3.z * bp[14] + a3.w * bp[15];
      float m0 = (e ? wm0.y : wm0.x) * (d0 + beff);
      float m1 = (e ? wm1.y : wm1.x) * (d1 + beff);
      float m2 = (e ? wm2.y : wm2.x) * (d2 + beff);
      float m3 = (e ? wm3.y : wm3.x) * (d3 + beff);
      float A0r = e ? A0v.z : A0v.x;
      float A0i = e ? A0v.w : A0v.y;
      float A1r = e ? A1v.z : A1v.x;
      float A1i = e ? A1v.w : A1v.y;
      float re = A1r * m0 - A1i * m1;
      float im = A1r * m1 - A1i * m0;
      float mwre = A0r + re * inv;
      float mwim = A0i + im * inv;
      float rd = rsqrtf(m2 * m2 + m3 * m3 + 1e-4f);
      outv[e] = (mwre * m2 + mwim * m3) * rd;
    }
    *reinterpret_cast<float2*>(out + b * 65536 + ij) = make_float2(outv[0], outv[1]);
  }
}

extern "C" void kernel_launch(void* const* d_in, const int* in_sizes, int n_in,
                              void* d_out, int out_size, void* d_ws, size_t ws_size,
                              hipStream_t stream) {
  const float* x     = (const float*)d_in[0];
  const float* Wt    = (const float*)d_in[1];
  const float* Wg    = (const float*)d_in[2];
  const float* wstat = (const float*)d_in[3];
  const float* wmod  = (const float*)d_in[4];
  const float* cw    = (const float*)d_in[5];
  const float* cb    = (const float*)d_in[6];

  float* mod     = (float*)d_ws;           // 524288 floats
  float* sbuf    = mod + 524288;           // 256 floats
  float* partial = sbuf + 256;             // 512 floats

  k1_gemm  <<<512, 256, 0, stream>>>(x, Wt, Wg, mod);
  k1b_scale<<<256, 256, 0, stream>>>(mod, wmod, wstat, sbuf);
  k2_mag   <<<dim3(64, 8), 256, 0, stream>>>(mod, sbuf, wstat, wmod, cw, cb, partial);
  k4_out   <<<dim3(64, 8), 256, 0, stream>>>(mod, sbuf, wstat, wmod, cw, cb, partial,
                                             (float*)d_out);
}

// Round 11
// 149.120 us; speedup vs baseline: 1.0328x; 1.0328x over previous
//
#include <hip/hip_runtime.h>

typedef __bf16 bf16x8 __attribute__((ext_vector_type(8)));
typedef float floatx4 __attribute__((ext_vector_type(4)));

// split fp32 -> bf16 hi + bf16 lo (x ~= hi + lo, residual ~2^-17)
__device__ inline void cvt8_hl(const float* __restrict__ p, bf16x8& h, bf16x8& l){
  float4 v0 = *reinterpret_cast<const float4*>(p);
  float4 v1 = *reinterpret_cast<const float4*>(p + 4);
  float v[8] = {v0.x, v0.y, v0.z, v0.w, v1.x, v1.y, v1.z, v1.w};
  #pragma unroll
  for (int i = 0; i < 8; ++i) {
    __bf16 hi = (__bf16)v[i];
    h[i] = hi;
    l[i] = (__bf16)(v[i] - (float)hi);
  }
}

__device__ inline void cvt8v(float4 v0, float4 v1, bf16x8& h, bf16x8& l){
  float v[8] = {v0.x, v0.y, v0.z, v0.w, v1.x, v1.y, v1.z, v1.w};
  #pragma unroll
  for (int i = 0; i < 8; ++i) {
    __bf16 hi = (__bf16)v[i];
    h[i] = hi;
    l[i] = (__bf16)(v[i] - (float)hi);
  }
}

// ---------------------------------------------------------------------------
// K1 v11: R0 structure (512 blk x 256 thr, 4-wave split-K=256, LDS tree at
// end) with ONE change: the wave's ENTIRE K-range of W (8 iters x 2 mats x
// 2 float4 = 32 float4 = 128 VGPR) is loaded into registers up-front in one
// back-to-back batch -> 32KB in flight per wave (vs ~7KB compiler-hoisted in
// R0) >> 9.2KB BW-latency product. Consumption order = issue order.
// __launch_bounds__(256,2) caps VGPR at 256 (2 waves/SIMD, same occupancy
// as R0). MFMA sequence byte-identical to R0-k1 => identical numerics.
// ---------------------------------------------------------------------------
__global__ __launch_bounds__(256, 2) void k1_gemm(
    const float* __restrict__ x,
    const float* __restrict__ Wt,
    const float* __restrict__ Wg,
    float* __restrict__ mod)
{
  __shared__ float red[3][32][64];   // waves 1..3 partials, 24 KB
  const int tid  = threadIdx.x;
  const int wave = tid >> 6, lane = tid & 63;
  const int quad = lane >> 4, r16 = lane & 15;
  const int ff = blockIdx.x * 16 + r16;
  const int kb = wave * 256 + quad * 8;

  const float* wt = Wt + ff * 1024 + kb;
  const float* wg = Wg + ff * 1024 + kb;
  const float* xp = x  + r16 * 1024 + kb;

  // ---- full-K W preload: 32 independent dwordx4, issued back-to-back ----
  float4 wbT[16], wbG[16];
  #pragma unroll
  for (int it = 0; it < 8; ++it) {
    wbT[it * 2]     = *reinterpret_cast<const float4*>(wt + it * 32);
    wbT[it * 2 + 1] = *reinterpret_cast<const float4*>(wt + it * 32 + 4);
    wbG[it * 2]     = *reinterpret_cast<const float4*>(wg + it * 32);
    wbG[it * 2 + 1] = *reinterpret_cast<const float4*>(wg + it * 32 + 4);
  }

  floatx4 accT[4], accG[4];
  #pragma unroll
  for (int m = 0; m < 4; ++m) { accT[m] = (floatx4)0.0f; accG[m] = (floatx4)0.0f; }

  #pragma unroll
  for (int it = 0; it < 8; ++it) {
    const int ko = it * 32;
    bf16x8 bth, btl, bgh, bgl;
    cvt8v(wbT[it * 2], wbT[it * 2 + 1], bth, btl);
    cvt8v(wbG[it * 2], wbG[it * 2 + 1], bgh, bgl);
    #pragma unroll
    for (int mt = 0; mt < 4; ++mt) {
      bf16x8 ah, al;
      cvt8_hl(xp + mt * 16384 + ko, ah, al);
      accT[mt] = __builtin_amdgcn_mfma_f32_16x16x32_bf16(ah, bth, accT[mt], 0, 0, 0);
      accT[mt] = __builtin_amdgcn_mfma_f32_16x16x32_bf16(ah, btl, accT[mt], 0, 0, 0);
      accT[mt] = __builtin_amdgcn_mfma_f32_16x16x32_bf16(al, bth, accT[mt], 0, 0, 0);
      accG[mt] = __builtin_amdgcn_mfma_f32_16x16x32_bf16(ah, bgh, accG[mt], 0, 0, 0);
      accG[mt] = __builtin_amdgcn_mfma_f32_16x16x32_bf16(ah, bgl, accG[mt], 0, 0, 0);
      accG[mt] = __builtin_amdgcn_mfma_f32_16x16x32_bf16(al, bgh, accG[mt], 0, 0, 0);
    }
  }

  if (wave != 0) {
    #pragma unroll
    for (int mt = 0; mt < 4; ++mt)
      #pragma unroll
      for (int r = 0; r < 4; ++r) {
        red[wave - 1][mt * 4 + r][lane]      = accT[mt][r];
        red[wave - 1][16 + mt * 4 + r][lane] = accG[mt][r];
      }
  }
  __syncthreads();
  if (wave == 0) {
    #pragma unroll
    for (int mt = 0; mt < 4; ++mt) {
      #pragma unroll
      for (int r = 0; r < 4; ++r) {
        float t = accT[mt][r] + red[0][mt * 4 + r][lane]
                              + red[1][mt * 4 + r][lane]
                              + red[2][mt * 4 + r][lane];
        float g = accG[mt][r] + red[0][16 + mt * 4 + r][lane]
                              + red[1][16 + mt * 4 + r][lane]
                              + red[2][16 + mt * 4 + r][lane];
        float sig = 1.0f / (1.0f + __expf(-g));
        int b = mt * 16 + quad * 4 + r;          // C/D: row = quad*4 + reg
        mod[b * 8192 + ff] = t * g * sig;
      }
    }
  }
}

// ---------------------------------------------------------------------------
// K1b (R9 proven): s[b*4+k] = rsqrt(mean(|mod[b,k,:]|) + eps) + weight warm.
// ---------------------------------------------------------------------------
__global__ __launch_bounds__(256) void k1b_scale(const float* __restrict__ mod,
                                                 const float* __restrict__ wmod,
                                                 const float* __restrict__ wstat,
                                                 float* __restrict__ s)
{
  const int row = blockIdx.x;
  const int tid = threadIdx.x;
  const float* p = mod + row * 2048;

  const int g = blockIdx.x * 256 + tid;
  const float4 wv = reinterpret_cast<const float4*>(wmod)[g];
  const float4 sv = reinterpret_cast<const float4*>(wstat)[g];
  float keep = wv.x + wv.y + wv.z + wv.w + sv.x + sv.y + sv.z + sv.w;
  asm volatile("" :: "v"(keep));

  float sum = 0.0f;
  #pragma unroll
  for (int q = 0; q < 8; ++q) sum += fabsf(p[q * 256 + tid]);
  #pragma unroll
  for (int o = 1; o < 64; o <<= 1) sum += __shfl_xor(sum, o, 64);
  __shared__ float ls[4];
  if ((tid & 63) == 0) ls[tid >> 6] = sum;
  __syncthreads();
  if (tid == 0) {
    float t = ls[0] + ls[1] + ls[2] + ls[3];
    s[row] = rsqrtf(t * (1.0f / 2048.0f) + 1e-4f);
  }
}

// ---------------------------------------------------------------------------
// K2 (R9 proven, byte-identical).
// ---------------------------------------------------------------------------
__global__ __launch_bounds__(256) void k2_mag(
    const float* __restrict__ mod, const float* __restrict__ s,
    const float* __restrict__ wstat,
    const float* __restrict__ wmod,
    const float* __restrict__ cw,
    const float* __restrict__ cb,
    float* __restrict__ partial)
{
  const int b = blockIdx.x, jc = blockIdx.y;
  const int tid = threadIdx.x;
  __shared__ __align__(16) float a_l[256 * 8];

  float weff[4]; float beff = 0.0f;
  #pragma unroll
  for (int r = 0; r < 4; ++r) {
    weff[r] = cw[r] + cw[4 + r] + cw[8 + r] + cw[12 + r];
    beff += cb[r];
  }
  const float s0 = s[b * 4 + 0], s1 = s[b * 4 + 1];
  const float* mb = mod + b * 8192;

  #pragma unroll
  for (int p = 0; p < 8; ++p) {
    int k = p >> 2, r = p & 3;
    float sc = (k ? s1 : s0) * weff[r];
    a_l[tid * 8 + p] = mb[k * 2048 + r * 512 + tid] * sc;
  }
  const int j = jc * 32 + (tid & 31);
  float bp[8];
  #pragma unroll
  for (int p = 0; p < 8; ++p) {
    int k = p >> 2, r = p & 3;
    bp[p] = mb[k * 2048 + r * 512 + 256 + j] * (k ? s1 : s0);
  }
  __syncthreads();

  const int ioff = tid >> 5;
  float acc = 0.0f;
  #pragma unroll 8
  for (int it = 0; it < 32; ++it) {
    const int i = it * 8 + ioff;
    const float4 av0 = *reinterpret_cast<const float4*>(&a_l[i * 8]);
    const float4 av1 = *reinterpret_cast<const float4*>(&a_l[i * 8 + 4]);
    float d0 = av0.x * bp[0] + av0.y * bp[1] + av0.z * bp[2] + av0.w * bp[3];
    float d1 = av1.x * bp[4] + av1.y * bp[5] + av1.z * bp[6] + av1.w * bp[7];
    const int ij = i * 256 + j;
    float m0 = wmod[ij] * (d0 + beff);
    float m1 = wmod[65536 + ij] * (d1 + beff);
    float2 a1 = *reinterpret_cast<const float2*>(wstat + 131072 + ij * 2);
    float re = a1.x * m0 - a1.y * m1;
    float im = a1.x * m1 - a1.y * m0;
    acc += sqrtf(re * re + im * im + 1e-4f);
  }
  #pragma unroll
  for (int o = 1; o < 64; o <<= 1) acc += __shfl_xor(acc, o, 64);
  __shared__ float wsum[4];
  if ((tid & 63) == 0) wsum[tid >> 6] = acc;
  __syncthreads();
  if (tid == 0) partial[b * 8 + jc] = wsum[0] + wsum[1] + wsum[2] + wsum[3];
}

// ---------------------------------------------------------------------------
// K4 (R9 proven, byte-identical).
// ---------------------------------------------------------------------------
__global__ __launch_bounds__(256) void k4_out(
    const float* __restrict__ mod, const float* __restrict__ s,
    const float* __restrict__ wstat,
    const float* __restrict__ wmod,
    const float* __restrict__ cw,
    const float* __restrict__ cb,
    const float* __restrict__ partial,
    float* __restrict__ out)
{
  const int b = blockIdx.x, ibase = blockIdx.y * 32;
  const int tid = threadIdx.x;
  __shared__ __align__(16) float a_l[32 * 16];

  float weff[4]; float beff = 0.0f;
  #pragma unroll
  for (int r = 0; r < 4; ++r) {
    weff[r] = cw[r] + cw[4 + r] + cw[8 + r] + cw[12 + r];
    beff += cb[r];
  }
  float sk[4];
  #pragma unroll
  for (int k = 0; k < 4; ++k) sk[k] = s[b * 4 + k];
  const float* mb = mod + b * 8192;

  float tot = 0.0f;
  #pragma unroll
  for (int t = 0; t < 8; ++t) tot += partial[b * 8 + t];
  const float inv = rsqrtf(tot * (1.0f / 65536.0f) + 1e-4f);

  #pragma unroll
  for (int p = 0; p < 2; ++p) {
    int idx = p * 256 + tid;
    int il = idx & 31, kr = idx >> 5;
    int k = kr >> 2, r = kr & 3;
    a_l[il * 16 + kr] = mb[k * 2048 + r * 512 + ibase + il] * (sk[k] * weff[r]);
  }
  const int j = (tid & 127) * 2;
  const int ioff = tid >> 7;
  float bp0[16], bp1[16];
  #pragma unroll
  for (int kr = 0; kr < 16; ++kr) {
    int k = kr >> 2, r = kr & 3;
    float2 v = *reinterpret_cast<const float2*>(mb + k * 2048 + r * 512 + 256 + j);
    bp0[kr] = v.x * sk[k]; bp1[kr] = v.y * sk[k];
  }
  __syncthreads();

  #pragma unroll 4
  for (int it = 0; it < 16; ++it) {
    const int il = it * 2 + ioff;
    const int i = ibase + il;
    const float4 a0 = *reinterpret_cast<const float4*>(&a_l[il * 16]);
    const float4 a1 = *reinterpret_cast<const float4*>(&a_l[il * 16 + 4]);
    const float4 a2 = *reinterpret_cast<const float4*>(&a_l[il * 16 + 8]);
    const float4 a3 = *reinterpret_cast<const float4*>(&a_l[il * 16 + 12]);
    const int ij = i * 256 + j;
    const float2 wm0 = *reinterpret_cast<const float2*>(wmod + ij);
    const float2 wm1 = *reinterpret_cast<const float2*>(wmod + 65536 + ij);
    const float2 wm2 = *reinterpret_cast<const float2*>(wmod + 131072 + ij);
    const float2 wm3 = *reinterpret_cast<const float2*>(wmod + 196608 + ij);
    const float4 A0v = *reinterpret_cast<const float4*>(wstat + ij * 2);
    const float4 A1v = *reinterpret_cast<const float4*>(wstat + 131072 + ij * 2);
    float outv[2];
    #pragma unroll
    for (int e = 0; e < 2; ++e) {
      const float* bp = e ? bp1 : bp0;
      float d0 = a0.x * bp[0] + a0.y * bp[1] + a0.z * bp[2] + a0.w * bp[3];
      float d1 = a1.x * bp[4] + a1.y * bp[5] + a1.z * bp[6] + a1.w * bp[7];
      float d2 = a2.x * bp[8] + a2.y * bp[9] + a2.z * bp[10] + a2.w * bp[11];
      float d3 = a3.x * bp[12] + a3.y * bp[13] + a3.z * bp[14] + a3.w * bp[15];
      float m0 = (e ? wm0.y : wm0.x) * (d0 + beff);
      float m1 = (e ? wm1.y : wm1.x) * (d1 + beff);
      float m2 = (e ? wm2.y : wm2.x) * (d2 + beff);
      float m3 = (e ? wm3.y : wm3.x) * (d3 + beff);
      float A0r = e ? A0v.z : A0v.x;
      float A0i = e ? A0v.w : A0v.y;
      float A1r = e ? A1v.z : A1v.x;
      float A1i = e ? A1v.w : A1v.y;
      float re = A1r * m0 - A1i * m1;
      float im = A1r * m1 - A1i * m0;
      float mwre = A0r + re * inv;
      float mwim = A0i + im * inv;
      float rd = rsqrtf(m2 * m2 + m3 * m3 + 1e-4f);
      outv[e] = (mwre * m2 + mwim * m3) * rd;
    }
    *reinterpret_cast<float2*>(out + b * 65536 + ij) = make_float2(outv[0], outv[1]);
  }
}

extern "C" void kernel_launch(void* const* d_in, const int* in_sizes, int n_in,
                              void* d_out, int out_size, void* d_ws, size_t ws_size,
                              hipStream_t stream) {
  const float* x     = (const float*)d_in[0];
  const float* Wt    = (const float*)d_in[1];
  const float* Wg    = (const float*)d_in[2];
  const float* wstat = (const float*)d_in[3];
  const float* wmod  = (const float*)d_in[4];
  const float* cw    = (const float*)d_in[5];
  const float* cb    = (const float*)d_in[6];

  float* mod     = (float*)d_ws;           // 524288 floats
  float* sbuf    = mod + 524288;           // 256 floats
  float* partial = sbuf + 256;             // 512 floats

  k1_gemm  <<<512, 256, 0, stream>>>(x, Wt, Wg, mod);
  k1b_scale<<<256, 256, 0, stream>>>(mod, wmod, wstat, sbuf);
  k2_mag   <<<dim3(64, 8), 256, 0, stream>>>(mod, sbuf, wstat, wmod, cw, cb, partial);
  k4_out   <<<dim3(64, 8), 256, 0, stream>>>(mod, sbuf, wstat, wmod, cw, cb, partial,
                                             (float*)d_out);
}